// Round 6
// baseline (96.512 us; speedup 1.0000x reference)
//
#include <hip/hip_runtime.h>

#define CQ 32
#define KQ 128
#define NPTS 384
#define OUTN 1024
#define BQ 8
#define NACC (BQ * OUTN)
#define HSZ 1024
#define WS_NEED ((size_t)BQ * KQ * OUTN * sizeof(float))

__global__ void zero_out(float* __restrict__ out) {
    int i = blockIdx.x * blockDim.x + threadIdx.x;
    if (i < NACC) out[i] = 0.0f;
}

// wave64 sum via DPP; result valid in lane 63 (invalid-source lanes read 0).
__device__ __forceinline__ float wave_red_dpp(float v) {
#define DPPADD(ctrl)                                                              \
    {                                                                             \
        int t_ = __builtin_amdgcn_update_dpp(0, __float_as_int(v), (ctrl), 0xF,   \
                                             0xF, true);                          \
        v += __int_as_float(t_);                                                  \
    }
    DPPADD(0x111)  // row_shr:1
    DPPADD(0x112)  // row_shr:2
    DPPADD(0x114)  // row_shr:4
    DPPADD(0x118)  // row_shr:8   -> lane 15 of each row16 = row sum
    DPPADD(0x142)  // row_bcast:15 -> lane31 += rows0-1 sum etc.
    DPPADD(0x143)  // row_bcast:31 -> lane63 = wave sum
#undef DPPADD
    return v;
}

// use_ws==1: accumulate into LDS, stream 4KB partial to dst=ws (layout [b][k][c])
// use_ws==0: fallback, global atomicAdd into dst=out (pre-zeroed)
__global__ __launch_bounds__(NPTS) void sparse_part(
    const float* __restrict__ x,
    const float* __restrict__ means,
    const float* __restrict__ sigmas,
    const float* __restrict__ values,
    const float* __restrict__ su,
    const float* __restrict__ ru,
    float* __restrict__ dst,
    int use_ws)
{
    const int k = blockIdx.x, b = blockIdx.y;
    const int tid = threadIdx.x;
    const int lane = tid & 63, wid = tid >> 6;
    const int gk = b * KQ + k;
    const int c = tid / 12, j = tid % 12;   // point tid = c*12 + j
    const int cb = gk * CQ + c;
    const float CEPS = (float)(1.0 - 1e-6); // exact f32 of reference constant

    __shared__ float4 gp[CQ];               // {m0, m1, inv0, inv1}
    __shared__ float valc[CQ];
    __shared__ int htab[HSZ];
    __shared__ float part[6][CQ];
    __shared__ float wnorm[CQ];
    __shared__ float acc[OUTN];

    // ---- issue ALL global loads up front (latency overlapped with LDS init) ----
    const float2 mcb = *(const float2*)&means[cb * 2];  // own gaussian's mean
    float2 uu = make_float2(0.0f, 0.0f);
    if (j >= 8)       uu = *(const float2*)&ru[(cb * 4 + (j - 8)) * 2];
    else if (j >= 4)  uu = *(const float2*)&su[(cb * 4 + (j - 4)) * 2];
    float2 mg, sg; float vv = 0.0f;
    if (tid < CQ) {
        int cbs = gk * CQ + tid;
        mg = *(const float2*)&means[cbs * 2];
        sg = *(const float2*)&sigmas[cbs * 2];
        vv = values[cbs];
    }

    // ---- LDS init (overlaps the loads above) ----
    for (int i = tid; i < HSZ; i += NPTS) htab[i] = -1;
    if (use_ws) {
        for (int i = tid; i < OUTN; i += NPTS) acc[i] = 0.0f;
    }
    if (tid < CQ) {
        float i0 = __fsqrt_rn(__fdiv_rn(1.0f, __fadd_rn(1e-6f, sg.x)));
        float i1 = __fsqrt_rn(__fdiv_rn(1.0f, __fadd_rn(1e-6f, sg.y)));
        gp[tid] = make_float4(mg.x, mg.y, i0, i1);
        valc[tid] = vv;
    }

    // ---- generate this thread's point (registers only, pre-barrier) ----
    const float mm0 = mcb.x, mm1 = mcb.y;
    int p0, p1;
    if (j < 4) {
        // fm order: (T,T),(T,F),(F,T),(F,F); True->floor, False->ceil
        p0 = (int)((j >= 2) ? ceilf(mm0) : floorf(mm0));
        p1 = (int)((j & 1) ? ceilf(mm1) : floorf(mm1));
    } else if (j < 8) {
        // floor((u*(1-eps))*rng), pure f32 RN, no fma contraction
        p0 = (int)floorf(__fmul_rn(__fmul_rn(uu.x, CEPS), 1024.0f));
        p1 = (int)floorf(__fmul_rn(__fmul_rn(uu.y, CEPS), 1024.0f));
    } else {
        float mn0 = rintf(mm0), mn1 = rintf(mm1);  // jnp.round = half-even
        float lo0 = mn0 - 8.0f; if (lo0 < 0.0f) lo0 = 0.0f; if (mn0 + 8.0f > 1024.0f) lo0 = 1008.0f;
        float lo1 = mn1 - 8.0f; if (lo1 < 0.0f) lo1 = 0.0f; if (mn1 + 8.0f > 1024.0f) lo1 = 1008.0f;
        p0 = (int)floorf(__fadd_rn(__fmul_rn(__fmul_rn(uu.x, CEPS), 16.0f), lo0));
        p1 = (int)floorf(__fadd_rn(__fmul_rn(__fmul_rn(uu.y, CEPS), 16.0f), lo1));
    }
    __syncthreads();

    // ---- dedup via LDS hash (any survivor per id is numerically identical to
    // the reference's stable-sort pick: equal id => equal coords => equal
    // density row => equal vals and scatter target) ----
    const int myid = p0 * 1024 + p1;
    int slot = (int)(((unsigned)myid * 2654435761u) >> 22);
    bool dup = false;
    while (true) {
        int prev = atomicCAS(&htab[slot], -1, myid);
        if (prev == -1) break;
        if (prev == myid) { dup = true; break; }
        slot = (slot + 1) & (HSZ - 1);
    }

    // ---- densities vs all 32 gaussians (dups zeroed pre-normalization) ----
    const float pf0 = (float)p0, pf1 = (float)p1;
    float pr[CQ];
    #pragma unroll
    for (int cc = 0; cc < CQ; ++cc) {
        float4 g = gp[cc];                       // ds_read_b128
        float d0 = (pf0 - g.x) * g.z;
        float d1 = (pf1 - g.y) * g.w;
        float e = __expf(-0.5f * (d0 * d0 + d1 * d1));
        pr[cc] = dup ? 0.0f : e;
    }

    // ---- per-gaussian sums over 384 points: DPP wave sum + cross-wave ----
    #pragma unroll
    for (int cc = 0; cc < CQ; ++cc) {
        float v = wave_red_dpp(pr[cc]);
        if (lane == 63) part[wid][cc] = v;
    }
    __syncthreads();
    if (tid < CQ) {
        float s = 0.0f;
        #pragma unroll
        for (int w = 0; w < 6; ++w) s += part[w][tid];
        wnorm[tid] = valc[tid] / s;  // value_c / S_c (S_c > 0: own corners survive)
    }
    __syncthreads();

    // ---- vals + scatter ----
    if (!dup) {
        float vals = 0.0f;
        #pragma unroll
        for (int cc = 0; cc < CQ; ++cc) vals += pr[cc] * wnorm[cc];
        int g1 = p1 < 0 ? 0 : (p1 > OUTN - 1 ? OUTN - 1 : p1);  // jnp gather clamps
        float contrib = vals * x[b * OUTN + g1];
        if (p0 >= 0 && p0 < OUTN) {                              // jnp scatter drops OOB
            if (use_ws) atomicAdd(&acc[p0], contrib);            // LDS ds_add
            else        atomicAdd(&dst[b * OUTN + p0], contrib); // fallback
        }
    }

    if (use_ws) {
        __syncthreads();
        float* w = dst + (size_t)gk * OUTN;
        for (int i = tid; i < OUTN; i += NPTS) w[i] = acc[i];    // coalesced stream-out
    }
}

// out[b][c] = sum_k ws[(b*KQ+k)*OUTN + c]; verbatim R4 reduce (absmax 0.0 verified)
__global__ void reduce_ws(const float* __restrict__ ws, float* __restrict__ out) {
    int t = blockIdx.x * blockDim.x + threadIdx.x;
    if (t >= NACC) return;
    int b = t >> 10, cidx = t & (OUTN - 1);
    const float* p = ws + (size_t)b * KQ * OUTN + cidx;
    float s0 = 0.0f, s1 = 0.0f, s2 = 0.0f, s3 = 0.0f;
    #pragma unroll
    for (int k = 0; k < KQ; k += 4) {
        s0 += p[(size_t)(k + 0) * OUTN];
        s1 += p[(size_t)(k + 1) * OUTN];
        s2 += p[(size_t)(k + 2) * OUTN];
        s3 += p[(size_t)(k + 3) * OUTN];
    }
    out[t] = (s0 + s1) + (s2 + s3);
}

extern "C" void kernel_launch(void* const* d_in, const int* in_sizes, int n_in,
                              void* d_out, int out_size, void* d_ws, size_t ws_size,
                              hipStream_t stream) {
    const float* x      = (const float*)d_in[0];
    const float* means  = (const float*)d_in[1];
    const float* sigmas = (const float*)d_in[2];
    const float* values = (const float*)d_in[3];
    const float* su     = (const float*)d_in[4];
    const float* ru     = (const float*)d_in[5];
    float* out = (float*)d_out;
    float* ws  = (float*)d_ws;

    if (ws_size >= WS_NEED) {
        sparse_part<<<dim3(KQ, BQ), dim3(NPTS), 0, stream>>>(
            x, means, sigmas, values, su, ru, ws, 1);
        reduce_ws<<<dim3((NACC + 127) / 128), dim3(128), 0, stream>>>(ws, out);
    } else {
        zero_out<<<dim3((NACC + 255) / 256), dim3(256), 0, stream>>>(out);
        sparse_part<<<dim3(KQ, BQ), dim3(NPTS), 0, stream>>>(
            x, means, sigmas, values, su, ru, out, 0);
    }
}

// Round 7
// 90.489 us; speedup vs baseline: 1.0666x; 1.0666x over previous
//
#include <hip/hip_runtime.h>

#define CQ 32
#define KQ 128
#define OUTN 1024
#define BQ 8
#define NACC (BQ * OUTN)
#define HSZ 1024
#define PPL 6                         // points per lane (384 / 64)
#define WPB 4                         // waves (groups) per block
#define NGROUP (BQ * KQ)              // 1024
#define NBLK (NGROUP / WPB)           // 256
#define WS_NEED ((size_t)NGROUP * OUTN * sizeof(float))

__global__ void zero_out(float* __restrict__ out) {
    int i = blockIdx.x * blockDim.x + threadIdx.x;
    if (i < NACC) out[i] = 0.0f;
}

// wave64 sum via DPP; result valid in lane 63 (invalid-source lanes read 0).
__device__ __forceinline__ float wave_red_dpp(float v) {
#define DPPADD(ctrl)                                                              \
    {                                                                             \
        int t_ = __builtin_amdgcn_update_dpp(0, __float_as_int(v), (ctrl), 0xF,   \
                                             0xF, true);                          \
        v += __int_as_float(t_);                                                  \
    }
    DPPADD(0x111)  // row_shr:1
    DPPADD(0x112)  // row_shr:2
    DPPADD(0x114)  // row_shr:4
    DPPADD(0x118)  // row_shr:8
    DPPADD(0x142)  // row_bcast:15
    DPPADD(0x143)  // row_bcast:31 -> lane63 = wave sum
#undef DPPADD
    return v;
}

// One wave handles one (b,k) group of 32 gaussians / 384 points. No barriers.
// use_ws==1: partial per group streamed to dst=ws[g][1024]
// use_ws==0: fallback, global atomicAdd into dst=out (pre-zeroed)
__global__ __launch_bounds__(WPB * 64) void sparse_wave(
    const float* __restrict__ x,
    const float* __restrict__ means,
    const float* __restrict__ sigmas,
    const float* __restrict__ values,
    const float* __restrict__ su,
    const float* __restrict__ ru,
    float* __restrict__ dst,
    int use_ws)
{
    const int lane = threadIdx.x & 63;
    const int w = threadIdx.x >> 6;                 // wave in block
    const int gk = blockIdx.x * WPB + w;            // group id = b*KQ + k
    const int b = gk >> 7;                          // KQ == 128
    const float CEPS = (float)(1.0 - 1e-6);         // exact f32 of reference const

    __shared__ int htab[WPB][HSZ];                  // wave-private hash
    __shared__ float acc[WPB][OUTN];                // wave-private accumulator

    // wave-private LDS init (same wave writes & later reads: no barrier needed)
    #pragma unroll
    for (int i = 0; i < HSZ / 64; ++i) htab[w][i * 64 + lane] = -1;
    if (use_ws) {
        #pragma unroll
        for (int i = 0; i < OUTN / 64; ++i) acc[w][i * 64 + lane] = 0.0f;
    }

    // lanes 0..31 own gaussian cc==lane params in registers
    float pm0 = 0.f, pm1 = 0.f, pi0 = 0.f, pi1 = 0.f, pv = 0.f;
    if (lane < CQ) {
        int cb = gk * CQ + lane;
        float2 mg = *(const float2*)&means[cb * 2];
        float2 sg = *(const float2*)&sigmas[cb * 2];
        pm0 = mg.x; pm1 = mg.y;
        pi0 = __fsqrt_rn(__fdiv_rn(1.0f, __fadd_rn(1e-6f, sg.x)));
        pi1 = __fsqrt_rn(__fdiv_rn(1.0f, __fadd_rn(1e-6f, sg.y)));
        pv  = values[cb];
    }

    // ---- generate 6 points per lane (point pt = i*64+lane; c=pt/12, j=pt%12) ----
    int p0[PPL], p1[PPL];
    #pragma unroll
    for (int i = 0; i < PPL; ++i) {
        const int pt = i * 64 + lane;
        const int c = pt / 12, j = pt % 12;
        const float mm0 = __shfl(pm0, c), mm1 = __shfl(pm1, c);  // ds_bpermute
        int q0, q1;
        if (j < 4) {
            // fm order: (T,T),(T,F),(F,T),(F,F); True->floor, False->ceil
            q0 = (int)((j >= 2) ? ceilf(mm0) : floorf(mm0));
            q1 = (int)((j & 1) ? ceilf(mm1) : floorf(mm1));
        } else if (j < 8) {
            float2 uu = *(const float2*)&su[(gk * CQ + c) * 8 + (j - 4) * 2];
            // floor((u*(1-eps))*rng), pure f32 RN, no fma contraction
            q0 = (int)floorf(__fmul_rn(__fmul_rn(uu.x, CEPS), 1024.0f));
            q1 = (int)floorf(__fmul_rn(__fmul_rn(uu.y, CEPS), 1024.0f));
        } else {
            float2 uu = *(const float2*)&ru[(gk * CQ + c) * 8 + (j - 8) * 2];
            float mn0 = rintf(mm0), mn1 = rintf(mm1);  // jnp.round = half-even
            float lo0 = mn0 - 8.0f; if (lo0 < 0.0f) lo0 = 0.0f; if (mn0 + 8.0f > 1024.0f) lo0 = 1008.0f;
            float lo1 = mn1 - 8.0f; if (lo1 < 0.0f) lo1 = 0.0f; if (mn1 + 8.0f > 1024.0f) lo1 = 1008.0f;
            q0 = (int)floorf(__fadd_rn(__fmul_rn(__fmul_rn(uu.x, CEPS), 16.0f), lo0));
            q1 = (int)floorf(__fadd_rn(__fmul_rn(__fmul_rn(uu.y, CEPS), 16.0f), lo1));
        }
        p0[i] = q0; p1[i] = q1;
    }

    // prefetch x gathers (overlaps density compute)
    float xv[PPL];
    #pragma unroll
    for (int i = 0; i < PPL; ++i) {
        int g1 = p1[i] < 0 ? 0 : (p1[i] > OUTN - 1 ? OUTN - 1 : p1[i]);  // jnp gather clamps
        xv[i] = x[b * OUTN + g1];
    }

    // ---- dedup via wave-private LDS hash (any survivor per id is numerically
    // identical to the reference's stable-sort pick) ----
    unsigned dupm = 0u;
    #pragma unroll
    for (int i = 0; i < PPL; ++i) {
        const int myid = p0[i] * 1024 + p1[i];
        int slot = (int)(((unsigned)myid * 2654435761u) >> 22);
        while (true) {
            int prev = atomicCAS(&htab[w][slot], -1, myid);
            if (prev == -1) break;
            if (prev == myid) { dupm |= (1u << i); break; }
            slot = (slot + 1) & (HSZ - 1);
        }
    }

    const float pf0[PPL] = {(float)p0[0], (float)p0[1], (float)p0[2],
                            (float)p0[3], (float)p0[4], (float)p0[5]};
    const float pf1[PPL] = {(float)p1[0], (float)p1[1], (float)p1[2],
                            (float)p1[3], (float)p1[4], (float)p1[5]};

    // ---- per-gaussian: densities, DPP wave-sum S_c, accumulate vals ----
    float vals[PPL] = {0.f, 0.f, 0.f, 0.f, 0.f, 0.f};
    #pragma unroll
    for (int cc = 0; cc < CQ; ++cc) {
        const float m0 = __shfl(pm0, cc), m1 = __shfl(pm1, cc);  // v_readlane
        const float i0 = __shfl(pi0, cc), i1 = __shfl(pi1, cc);
        const float vv = __shfl(pv, cc);
        float e[PPL];
        float s = 0.f;
        #pragma unroll
        for (int i = 0; i < PPL; ++i) {
            float d0 = (pf0[i] - m0) * i0;
            float d1 = (pf1[i] - m1) * i1;
            float t = __expf(-0.5f * (d0 * d0 + d1 * d1));
            t = ((dupm >> i) & 1u) ? 0.0f : t;
            e[i] = t; s += t;
        }
        s = wave_red_dpp(s);
        const float ss = __shfl(s, 63);   // S_c > 0 (own corners survive dedup)
        const float wn = vv / ss;         // value_c / S_c
        #pragma unroll
        for (int i = 0; i < PPL; ++i) vals[i] += e[i] * wn;
    }

    // ---- scatter (wave-private LDS acc or global fallback) ----
    #pragma unroll
    for (int i = 0; i < PPL; ++i) {
        if (!((dupm >> i) & 1u) && p0[i] >= 0 && p0[i] < OUTN) {  // jnp scatter drops OOB
            float contrib = vals[i] * xv[i];
            if (use_ws) atomicAdd(&acc[w][p0[i]], contrib);       // LDS ds_add
            else        atomicAdd(&dst[b * OUTN + p0[i]], contrib);
        }
    }

    // ---- stream this group's 4KB partial out, coalesced float4 ----
    if (use_ws) {
        float* wsp = dst + (size_t)gk * OUTN;
        #pragma unroll
        for (int ii = 0; ii < OUTN / 256; ++ii) {
            int idx = ii * 256 + lane * 4;
            float4 v = *(const float4*)&acc[w][idx];
            *(float4*)&wsp[idx] = v;
        }
    }
}

// out[b][c] = sum_k ws[(b*KQ+k)*OUTN + c]; verbatim R4 reduce (absmax 0.0 verified)
__global__ void reduce_ws(const float* __restrict__ ws, float* __restrict__ out) {
    int t = blockIdx.x * blockDim.x + threadIdx.x;
    if (t >= NACC) return;
    int b = t >> 10, cidx = t & (OUTN - 1);
    const float* p = ws + (size_t)b * KQ * OUTN + cidx;
    float s0 = 0.0f, s1 = 0.0f, s2 = 0.0f, s3 = 0.0f;
    #pragma unroll
    for (int k = 0; k < KQ; k += 4) {
        s0 += p[(size_t)(k + 0) * OUTN];
        s1 += p[(size_t)(k + 1) * OUTN];
        s2 += p[(size_t)(k + 2) * OUTN];
        s3 += p[(size_t)(k + 3) * OUTN];
    }
    out[t] = (s0 + s1) + (s2 + s3);
}

extern "C" void kernel_launch(void* const* d_in, const int* in_sizes, int n_in,
                              void* d_out, int out_size, void* d_ws, size_t ws_size,
                              hipStream_t stream) {
    const float* x      = (const float*)d_in[0];
    const float* means  = (const float*)d_in[1];
    const float* sigmas = (const float*)d_in[2];
    const float* values = (const float*)d_in[3];
    const float* su     = (const float*)d_in[4];
    const float* ru     = (const float*)d_in[5];
    float* out = (float*)d_out;
    float* ws  = (float*)d_ws;

    if (ws_size >= WS_NEED) {
        sparse_wave<<<dim3(NBLK), dim3(WPB * 64), 0, stream>>>(
            x, means, sigmas, values, su, ru, ws, 1);
        reduce_ws<<<dim3((NACC + 127) / 128), dim3(128), 0, stream>>>(ws, out);
    } else {
        zero_out<<<dim3((NACC + 255) / 256), dim3(256), 0, stream>>>(out);
        sparse_wave<<<dim3(NBLK), dim3(WPB * 64), 0, stream>>>(
            x, means, sigmas, values, su, ru, out, 0);
    }
}

// Round 8
// 86.415 us; speedup vs baseline: 1.1168x; 1.0471x over previous
//
#include <hip/hip_runtime.h>

#define CQ 32
#define KQ 128
#define OUTN 1024
#define BQ 8
#define NACC (BQ * OUTN)
#define HSZ 1024
#define PPW 3                         // points per lane per wave (384 / 64 / 2)
#define WPG 2                         // waves per group
#define NGROUP (BQ * KQ)              // 1024 groups = 1024 blocks of 128 threads
#define WS_NEED ((size_t)NGROUP * OUTN * sizeof(float))

__global__ void zero_out(float* __restrict__ out) {
    int i = blockIdx.x * blockDim.x + threadIdx.x;
    if (i < NACC) out[i] = 0.0f;
}

// wave64 sum via DPP; result valid in lane 63 (invalid-source lanes read 0).
__device__ __forceinline__ float wave_red_dpp(float v) {
#define DPPADD(ctrl)                                                              \
    {                                                                             \
        int t_ = __builtin_amdgcn_update_dpp(0, __float_as_int(v), (ctrl), 0xF,   \
                                             0xF, true);                          \
        v += __int_as_float(t_);                                                  \
    }
    DPPADD(0x111)  // row_shr:1
    DPPADD(0x112)  // row_shr:2
    DPPADD(0x114)  // row_shr:4
    DPPADD(0x118)  // row_shr:8
    DPPADD(0x142)  // row_bcast:15
    DPPADD(0x143)  // row_bcast:31 -> lane63 = wave sum
#undef DPPADD
    return v;
}

// One 128-thread block = one (b,k) group; each of its 2 waves owns 192 points
// (3 per lane). e[cc][i] kept in registers across the cross-wave S_c combine.
// use_ws==1: group partial streamed to dst=ws[g][1024]
// use_ws==0: fallback, global atomicAdd into dst=out (pre-zeroed)
__global__ __launch_bounds__(WPG * 64, 2) void sparse_wave(
    const float* __restrict__ x,
    const float* __restrict__ means,
    const float* __restrict__ sigmas,
    const float* __restrict__ values,
    const float* __restrict__ su,
    const float* __restrict__ ru,
    float* __restrict__ dst,
    int use_ws)
{
    const int tid = threadIdx.x;
    const int lane = tid & 63;
    const int w = tid >> 6;                         // wave within group (0/1)
    const int gk = blockIdx.x;                      // group id = b*KQ + k
    const int b = gk >> 7;                          // KQ == 128
    const float CEPS = (float)(1.0 - 1e-6);         // exact f32 of reference const

    __shared__ __align__(16) int htab[HSZ];         // group-shared hash (4 KB)
    __shared__ __align__(16) float acc[OUTN];       // group accumulator (4 KB)
    __shared__ float spart[WPG][CQ];                // per-wave partial S_c

    // init (both waves cooperate)
    #pragma unroll
    for (int i = 0; i < HSZ / 128; ++i) htab[i * 128 + tid] = -1;
    if (use_ws) {
        #pragma unroll
        for (int i = 0; i < OUTN / 128; ++i) acc[i * 128 + tid] = 0.0f;
    }

    // lanes 0..31 of EACH wave hold gaussian cc==lane params in registers
    float pm0 = 0.f, pm1 = 0.f, pi0 = 0.f, pi1 = 0.f, pv = 0.f;
    if (lane < CQ) {
        int cb = gk * CQ + lane;
        float2 mg = *(const float2*)&means[cb * 2];
        float2 sg = *(const float2*)&sigmas[cb * 2];
        pm0 = mg.x; pm1 = mg.y;
        pi0 = __fsqrt_rn(__fdiv_rn(1.0f, __fadd_rn(1e-6f, sg.x)));
        pi1 = __fsqrt_rn(__fdiv_rn(1.0f, __fadd_rn(1e-6f, sg.y)));
        pv  = values[cb];
    }

    // ---- generate 3 points per lane (pt = w*192 + i*64 + lane) ----
    int p0[PPW], p1[PPW];
    #pragma unroll
    for (int i = 0; i < PPW; ++i) {
        const int pt = w * 192 + i * 64 + lane;
        const int c = pt / 12, j = pt % 12;
        const float mm0 = __shfl(pm0, c), mm1 = __shfl(pm1, c);  // ds_bpermute
        int q0, q1;
        if (j < 4) {
            // fm order: (T,T),(T,F),(F,T),(F,F); True->floor, False->ceil
            q0 = (int)((j >= 2) ? ceilf(mm0) : floorf(mm0));
            q1 = (int)((j & 1) ? ceilf(mm1) : floorf(mm1));
        } else if (j < 8) {
            float2 uu = *(const float2*)&su[(gk * CQ + c) * 8 + (j - 4) * 2];
            // floor((u*(1-eps))*rng), pure f32 RN, no fma contraction
            q0 = (int)floorf(__fmul_rn(__fmul_rn(uu.x, CEPS), 1024.0f));
            q1 = (int)floorf(__fmul_rn(__fmul_rn(uu.y, CEPS), 1024.0f));
        } else {
            float2 uu = *(const float2*)&ru[(gk * CQ + c) * 8 + (j - 8) * 2];
            float mn0 = rintf(mm0), mn1 = rintf(mm1);  // jnp.round = half-even
            float lo0 = mn0 - 8.0f; if (lo0 < 0.0f) lo0 = 0.0f; if (mn0 + 8.0f > 1024.0f) lo0 = 1008.0f;
            float lo1 = mn1 - 8.0f; if (lo1 < 0.0f) lo1 = 0.0f; if (mn1 + 8.0f > 1024.0f) lo1 = 1008.0f;
            q0 = (int)floorf(__fadd_rn(__fmul_rn(__fmul_rn(uu.x, CEPS), 16.0f), lo0));
            q1 = (int)floorf(__fadd_rn(__fmul_rn(__fmul_rn(uu.y, CEPS), 16.0f), lo1));
        }
        p0[i] = q0; p1[i] = q1;
    }

    // prefetch x gathers (overlap with hash + density)
    float xv[PPW];
    #pragma unroll
    for (int i = 0; i < PPW; ++i) {
        int g1 = p1[i] < 0 ? 0 : (p1[i] > OUTN - 1 ? OUTN - 1 : p1[i]);  // jnp gather clamps
        xv[i] = x[b * OUTN + g1];
    }

    __syncthreads();  // htab/acc init visible to both waves before probing

    // ---- dedup via group-shared LDS hash; CAS insert is interleaving-safe:
    // exactly one thread per id wins, any survivor is numerically identical
    // to the reference's stable-sort pick ----
    unsigned dupm = 0u;
    #pragma unroll
    for (int i = 0; i < PPW; ++i) {
        const int myid = p0[i] * 1024 + p1[i];
        int slot = (int)(((unsigned)myid * 2654435761u) >> 22);
        while (true) {
            int prev = atomicCAS(&htab[slot], -1, myid);
            if (prev == -1) break;
            if (prev == myid) { dupm |= (1u << i); break; }
            slot = (slot + 1) & (HSZ - 1);
        }
    }

    const float pf0[PPW] = {(float)p0[0], (float)p0[1], (float)p0[2]};
    const float pf1[PPW] = {(float)p1[0], (float)p1[1], (float)p1[2]};

    // ---- densities for all 32 gaussians; keep e in registers; partial S_c ----
    float e[CQ][PPW];
    #pragma unroll
    for (int cc = 0; cc < CQ; ++cc) {
        const float m0 = __shfl(pm0, cc), m1 = __shfl(pm1, cc);  // v_readlane
        const float i0 = __shfl(pi0, cc), i1 = __shfl(pi1, cc);
        float s = 0.f;
        #pragma unroll
        for (int i = 0; i < PPW; ++i) {
            float d0 = (pf0[i] - m0) * i0;
            float d1 = (pf1[i] - m1) * i1;
            float t = __expf(-0.5f * (d0 * d0 + d1 * d1));
            t = ((dupm >> i) & 1u) ? 0.0f : t;
            e[cc][i] = t; s += t;
        }
        s = wave_red_dpp(s);
        if (lane == 63) spart[w][cc] = s;
    }
    __syncthreads();  // both waves' partial S_c in LDS

    // ---- combine S_c, form wn = value_c / S_c, accumulate vals ----
    float vals[PPW] = {0.f, 0.f, 0.f};
    #pragma unroll
    for (int cc = 0; cc < CQ; ++cc) {
        const float ss = spart[0][cc] + spart[1][cc];  // S_c > 0 (corners survive)
        const float wn = __shfl(pv, cc) / ss;
        #pragma unroll
        for (int i = 0; i < PPW; ++i) vals[i] += e[cc][i] * wn;
    }

    // ---- scatter ----
    #pragma unroll
    for (int i = 0; i < PPW; ++i) {
        if (!((dupm >> i) & 1u) && p0[i] >= 0 && p0[i] < OUTN) {  // jnp drops OOB
            float contrib = vals[i] * xv[i];
            if (use_ws) atomicAdd(&acc[p0[i]], contrib);          // LDS ds_add
            else        atomicAdd(&dst[b * OUTN + p0[i]], contrib);
        }
    }

    // ---- stream the group's 4KB partial out, coalesced float4 ----
    if (use_ws) {
        __syncthreads();  // all scatters into acc complete
        float* wsp = dst + (size_t)gk * OUTN;
        #pragma unroll
        for (int ii = 0; ii < OUTN / (128 * 4); ++ii) {
            int idx = ii * 512 + tid * 4;
            float4 v = *(const float4*)&acc[idx];
            *(float4*)&wsp[idx] = v;
        }
    }
}

// out[b][c] = sum_k ws[(b*KQ+k)*OUTN + c]; verbatim R4 reduce (bit-exact verified)
__global__ void reduce_ws(const float* __restrict__ ws, float* __restrict__ out) {
    int t = blockIdx.x * blockDim.x + threadIdx.x;
    if (t >= NACC) return;
    int b = t >> 10, cidx = t & (OUTN - 1);
    const float* p = ws + (size_t)b * KQ * OUTN + cidx;
    float s0 = 0.0f, s1 = 0.0f, s2 = 0.0f, s3 = 0.0f;
    #pragma unroll
    for (int k = 0; k < KQ; k += 4) {
        s0 += p[(size_t)(k + 0) * OUTN];
        s1 += p[(size_t)(k + 1) * OUTN];
        s2 += p[(size_t)(k + 2) * OUTN];
        s3 += p[(size_t)(k + 3) * OUTN];
    }
    out[t] = (s0 + s1) + (s2 + s3);
}

extern "C" void kernel_launch(void* const* d_in, const int* in_sizes, int n_in,
                              void* d_out, int out_size, void* d_ws, size_t ws_size,
                              hipStream_t stream) {
    const float* x      = (const float*)d_in[0];
    const float* means  = (const float*)d_in[1];
    const float* sigmas = (const float*)d_in[2];
    const float* values = (const float*)d_in[3];
    const float* su     = (const float*)d_in[4];
    const float* ru     = (const float*)d_in[5];
    float* out = (float*)d_out;
    float* ws  = (float*)d_ws;

    if (ws_size >= WS_NEED) {
        sparse_wave<<<dim3(NGROUP), dim3(WPG * 64), 0, stream>>>(
            x, means, sigmas, values, su, ru, ws, 1);
        reduce_ws<<<dim3((NACC + 127) / 128), dim3(128), 0, stream>>>(ws, out);
    } else {
        zero_out<<<dim3((NACC + 255) / 256), dim3(256), 0, stream>>>(out);
        sparse_wave<<<dim3(NGROUP), dim3(WPG * 64), 0, stream>>>(
            x, means, sigmas, values, su, ru, out, 0);
    }
}